// Round 5
// baseline (258.874 us; speedup 1.0000x reference)
//
#include <hip/hip_runtime.h>
#include <hip/hip_cooperative_groups.h>
#include <math.h>

namespace cg = cooperative_groups;

#define CH 8
#define NH 4
#define HID 4
#define SPATIAL 65536       // 256*256
#define NSLICE 1024         // 32*4*8
#define NHALF  2048         // half-slices (32768 floats each)
#define HALF4  8192         // float4 per half-slice
#define EPS 1e-5f

typedef float nf4 __attribute__((ext_vector_type(4)));

// One cooperative kernel at FULL occupancy (8 blocks/CU):
//   phase 1: each block sum-pools its half-slice(s) -> partial[]
//   grid.sync()
//   phase 2: lanes 0..3 redundantly compute the tiny per-batch attention ->
//            factor; block re-reads its half-slice (L3-resident: FETCH stays
//            at one x read, proven in round 3) and nt-stores the output.
__global__ __launch_bounds__(256, 8)
void fused_all(const float* __restrict__ x,
               const float* __restrict__ Wq, const float* __restrict__ Wk,
               const float* __restrict__ Wv, const float* __restrict__ Wo,
               const float* __restrict__ bo,
               const float* __restrict__ W1, const float* __restrict__ b1,
               const float* __restrict__ W2, const float* __restrict__ b2,
               const float* __restrict__ g1, const float* __restrict__ beta1,
               const float* __restrict__ g2, const float* __restrict__ beta2,
               const float* __restrict__ gate,
               float* __restrict__ out,
               float* __restrict__ partial,
               int hpb) {
    const int tid = threadIdx.x;
    const int h0  = blockIdx.x * hpb;

    __shared__ float part[4];
    __shared__ float Kl[NH][CH], Vl[NH][CH], fac[NH][CH];

    // ---------- phase 1: pool ----------
    for (int i = 0; i < hpb; ++i) {
        const int half = h0 + i;
        if (half >= NHALF) break;
        const nf4* xs = (const nf4*)x + (size_t)half * HALF4;
        nf4 a0 = {0,0,0,0}, a1 = {0,0,0,0}, a2 = {0,0,0,0}, a3 = {0,0,0,0};
        int k = tid;
#pragma unroll
        for (int it = 0; it < 8; ++it) {   // 32 float4 per thread
            a0 += xs[k];
            a1 += xs[k + 256];
            a2 += xs[k + 512];
            a3 += xs[k + 768];
            k += 1024;
        }
        nf4 a = (a0 + a1) + (a2 + a3);
        float sum = (a.x + a.y) + (a.z + a.w);
        for (int off = 32; off; off >>= 1) sum += __shfl_down(sum, off, 64);
        if ((tid & 63) == 0) part[tid >> 6] = sum;
        __syncthreads();
        if (tid == 0)
            partial[half] = (part[0] + part[1]) + (part[2] + part[3]);
        __syncthreads();
    }

    cg::this_grid().sync();

    // ---------- phase 2 ----------
    for (int i = 0; i < hpb; ++i) {
        const int half = h0 + i;
        if (half >= NHALF) break;
        const int slice = half >> 1;       // (b*4 + h)*8 + c
        const int b     = slice >> 5;
        const int hh    = (slice >> 3) & 3;
        const int cc    = slice & 7;

        // factor for this half's batch (lanes 0..3, redundant per block)
        float xp[CH], Q[CH];
        if (tid < NH) {
            const float* pr = partial + b * (NH * CH * 2) + tid * (CH * 2);
#pragma unroll
            for (int c = 0; c < CH; ++c)
                xp[c] = (pr[c * 2] + pr[c * 2 + 1]) * (1.0f / SPATIAL);
            float mu = 0.f;
#pragma unroll
            for (int c = 0; c < CH; ++c) mu += xp[c];
            mu *= 0.125f;
            float var = 0.f;
#pragma unroll
            for (int c = 0; c < CH; ++c) { float d = xp[c] - mu; var += d * d; }
            var *= 0.125f;
            float rs = rsqrtf(var + EPS);
            float xn[CH];
#pragma unroll
            for (int c = 0; c < CH; ++c) xn[c] = (xp[c] - mu) * rs * g1[c] + beta1[c];
#pragma unroll
            for (int c = 0; c < CH; ++c) {
                float q = 0.f, k = 0.f, v = 0.f;
#pragma unroll
                for (int j = 0; j < CH; ++j) {
                    q += xn[j] * Wq[c * CH + j];
                    k += xn[j] * Wk[c * CH + j];
                    v += xn[j] * Wv[c * CH + j];
                }
                Q[c] = q; Kl[tid][c] = k; Vl[tid][c] = v;
            }
        }
        __syncthreads();
        if (tid < NH) {
            float sc[NH], mx = -1e30f;
#pragma unroll
            for (int g = 0; g < NH; ++g) {
                float s = 0.f;
#pragma unroll
                for (int c = 0; c < CH; ++c) s += Q[c] * Kl[g][c];
                s *= 0.35355339059327373f;   // CH^-0.5
                sc[g] = s; mx = fmaxf(mx, s);
            }
            float den = 0.f;
#pragma unroll
            for (int g = 0; g < NH; ++g) { sc[g] = __expf(sc[g] - mx); den += sc[g]; }
            const float inv = 1.0f / den;
            float ao[CH];
#pragma unroll
            for (int c = 0; c < CH; ++c) {
                float a = 0.f;
#pragma unroll
                for (int g = 0; g < NH; ++g) a += sc[g] * Vl[g][c];
                ao[c] = a * inv;
            }
            float xa[CH];
#pragma unroll
            for (int c = 0; c < CH; ++c) {
                float o = bo[c];
#pragma unroll
                for (int j = 0; j < CH; ++j) o += ao[j] * Wo[c * CH + j];
                xa[c] = xp[c] + o;
            }
            float mu = 0.f;
#pragma unroll
            for (int c = 0; c < CH; ++c) mu += xa[c];
            mu *= 0.125f;
            float var = 0.f;
#pragma unroll
            for (int c = 0; c < CH; ++c) { float d = xa[c] - mu; var += d * d; }
            var *= 0.125f;
            float rs = rsqrtf(var + EPS);
            float xn2[CH];
#pragma unroll
            for (int c = 0; c < CH; ++c) xn2[c] = (xa[c] - mu) * rs * g2[c] + beta2[c];
            float h1[HID];
#pragma unroll
            for (int ii = 0; ii < HID; ++ii) {
                float t = b1[ii];
#pragma unroll
                for (int c = 0; c < CH; ++c) t += xn2[c] * W1[ii * CH + c];
                h1[ii] = 0.5f * t * (1.0f + erff(t * 0.70710678118654752f));
            }
            const float gs = 1.0f / (1.0f + __expf(-gate[0]));
#pragma unroll
            for (int c = 0; c < CH; ++c) {
                float f = b2[c];
#pragma unroll
                for (int ii = 0; ii < HID; ++ii) f += h1[ii] * W2[c * HID + ii];
                float xo = xa[c] + f;
                fac[tid][c] = 1.0f + gs * (xo - xp[c]) + xp[c];
            }
        }
        __syncthreads();
        const float f = fac[hh][cc];

        const nf4* xs = (const nf4*)x + (size_t)half * HALF4;
        nf4*       os = (nf4*)out     + (size_t)half * HALF4;
        int k = tid;
#pragma unroll
        for (int it = 0; it < 8; ++it) {
            nf4 v0 = xs[k];
            nf4 v1 = xs[k + 256];
            nf4 v2 = xs[k + 512];
            nf4 v3 = xs[k + 768];
            v0 *= f; v1 *= f; v2 *= f; v3 *= f;
            __builtin_nontemporal_store(v0, &os[k]);
            __builtin_nontemporal_store(v1, &os[k + 256]);
            __builtin_nontemporal_store(v2, &os[k + 512]);
            __builtin_nontemporal_store(v3, &os[k + 768]);
            k += 1024;
        }
        __syncthreads();   // fac reused next iteration
    }
}

extern "C" void kernel_launch(void* const* d_in, const int* in_sizes, int n_in,
                              void* d_out, int out_size, void* d_ws, size_t ws_size,
                              hipStream_t stream) {
    const float* x     = (const float*)d_in[0];
    const float* Wq    = (const float*)d_in[1];
    const float* Wk    = (const float*)d_in[2];
    const float* Wv    = (const float*)d_in[3];
    const float* Wo    = (const float*)d_in[4];
    const float* bo    = (const float*)d_in[5];
    const float* W1    = (const float*)d_in[6];
    const float* b1    = (const float*)d_in[7];
    const float* W2    = (const float*)d_in[8];
    const float* b2    = (const float*)d_in[9];
    const float* g1    = (const float*)d_in[10];
    const float* beta1 = (const float*)d_in[11];
    const float* g2    = (const float*)d_in[12];
    const float* beta2 = (const float*)d_in[13];
    const float* gate  = (const float*)d_in[14];
    float* out = (float*)d_out;
    float* partial = (float*)d_ws;           // NHALF floats

    // max co-resident grid (host-side queries; graph-capture safe)
    int nCU = 256, occ = 8;
    hipDeviceProp_t prop;
    if (hipGetDeviceProperties(&prop, 0) == hipSuccess) nCU = prop.multiProcessorCount;
    hipOccupancyMaxActiveBlocksPerMultiprocessor(&occ, (const void*)fused_all, 256, 0);
    int grid = nCU * occ;
    if (grid > NHALF) grid = NHALF;
    int hpb = (NHALF + grid - 1) / grid;
    grid = (NHALF + hpb - 1) / hpb;

    void* args[] = {
        (void*)&x,
        (void*)&Wq, (void*)&Wk, (void*)&Wv, (void*)&Wo, (void*)&bo,
        (void*)&W1, (void*)&b1, (void*)&W2, (void*)&b2,
        (void*)&g1, (void*)&beta1, (void*)&g2, (void*)&beta2,
        (void*)&gate,
        (void*)&out, (void*)&partial, (void*)&hpb
    };
    hipLaunchCooperativeKernel((const void*)fused_all,
                               dim3(grid), dim3(256),
                               args, 0, stream);
}

// Round 6
// 129.476 us; speedup vs baseline: 1.9994x; 1.9994x over previous
//
#include <hip/hip_runtime.h>
#include <math.h>

#define CH 8
#define NH 4
#define HID 4
#define SPATIAL 65536       // 256*256
#define NSLICE 1024         // 32*4*8
#define NHALF  2048         // 2 half-slices per slice
#define HALF4  8192         // float4 per half-slice (32768 floats)
#define EPS 1e-5f

typedef float nf4 __attribute__((ext_vector_type(4)));

// ---------------- Kernel 1: spatial sum pool (half-slice granularity) ----------------
// 2048 blocks x 256 threads; block sums 32768 contiguous floats.
// Streams x FORWARD; at kernel end the L3 (256 MB) holds the tail of x.
__global__ __launch_bounds__(256)
void pool_kernel(const float* __restrict__ x, float* __restrict__ partial) {
    const int half = blockIdx.x;
    const nf4* xs = (const nf4*)x + (size_t)half * HALF4;
    const int tid = threadIdx.x;

    nf4 a0 = {0,0,0,0}, a1 = {0,0,0,0}, a2 = {0,0,0,0}, a3 = {0,0,0,0};
    int k = tid;
#pragma unroll
    for (int it = 0; it < 8; ++it) {      // 32 float4 per thread
        a0 += xs[k];
        a1 += xs[k + 256];
        a2 += xs[k + 512];
        a3 += xs[k + 768];
        k += 1024;
    }
    nf4 a = (a0 + a1) + (a2 + a3);
    float sum = (a.x + a.y) + (a.z + a.w);

    for (int off = 32; off; off >>= 1) sum += __shfl_down(sum, off, 64);
    __shared__ float part[4];
    if ((tid & 63) == 0) part[tid >> 6] = sum;
    __syncthreads();
    if (tid == 0)
        partial[half] = (part[0] + part[1]) + (part[2] + part[3]);
}

// ---------------- Kernel 2: fused factor-compute + broadcast scale ----------------
// 2048 blocks x 256 threads. Block i handles half-slice NHALF-1-i: REVERSE
// traversal, so reads start at the tail of x (freshest in L3 after pool) and
// walk backward through still-resident lines — defeats the LRU re-scan
// pathology. nt-stores keep the output from evicting x.
__global__ __launch_bounds__(256)
void scale_fused(const float* __restrict__ x,
                 const float* __restrict__ partial,
                 const float* __restrict__ Wq, const float* __restrict__ Wk,
                 const float* __restrict__ Wv, const float* __restrict__ Wo,
                 const float* __restrict__ bo,
                 const float* __restrict__ W1, const float* __restrict__ b1,
                 const float* __restrict__ W2, const float* __restrict__ b2,
                 const float* __restrict__ g1, const float* __restrict__ beta1,
                 const float* __restrict__ g2, const float* __restrict__ beta2,
                 const float* __restrict__ gate,
                 float* __restrict__ out) {
    const int half  = (NHALF - 1) - blockIdx.x;   // reverse order
    const int slice = half >> 1;                  // (b*4 + h)*8 + c
    const int b     = slice >> 5;
    const int hh    = (slice >> 3) & 3;
    const int cc    = slice & 7;
    const int tid   = threadIdx.x;

    __shared__ float Kl[NH][CH], Vl[NH][CH], fac[NH][CH];

    float xp[CH], Q[CH];
    if (tid < NH) {
        // pooled row h = tid of batch b, from half-partials
        const float* pr = partial + b * (NH * CH * 2) + tid * (CH * 2);
#pragma unroll
        for (int c = 0; c < CH; ++c)
            xp[c] = (pr[c * 2] + pr[c * 2 + 1]) * (1.0f / SPATIAL);
        // LayerNorm 1
        float mu = 0.f;
#pragma unroll
        for (int c = 0; c < CH; ++c) mu += xp[c];
        mu *= 0.125f;
        float var = 0.f;
#pragma unroll
        for (int c = 0; c < CH; ++c) { float d = xp[c] - mu; var += d * d; }
        var *= 0.125f;
        float rs = rsqrtf(var + EPS);
        float xn[CH];
#pragma unroll
        for (int c = 0; c < CH; ++c) xn[c] = (xp[c] - mu) * rs * g1[c] + beta1[c];
        // Q,K,V
#pragma unroll
        for (int c = 0; c < CH; ++c) {
            float q = 0.f, k = 0.f, v = 0.f;
#pragma unroll
            for (int j = 0; j < CH; ++j) {
                q += xn[j] * Wq[c * CH + j];
                k += xn[j] * Wk[c * CH + j];
                v += xn[j] * Wv[c * CH + j];
            }
            Q[c] = q; Kl[tid][c] = k; Vl[tid][c] = v;
        }
    }
    __syncthreads();
    if (tid < NH) {
        float sc[NH], mx = -1e30f;
#pragma unroll
        for (int g = 0; g < NH; ++g) {
            float s = 0.f;
#pragma unroll
            for (int c = 0; c < CH; ++c) s += Q[c] * Kl[g][c];
            s *= 0.35355339059327373f;   // CH^-0.5
            sc[g] = s; mx = fmaxf(mx, s);
        }
        float den = 0.f;
#pragma unroll
        for (int g = 0; g < NH; ++g) { sc[g] = __expf(sc[g] - mx); den += sc[g]; }
        const float inv = 1.0f / den;
        float ao[CH];
#pragma unroll
        for (int c = 0; c < CH; ++c) {
            float a = 0.f;
#pragma unroll
            for (int g = 0; g < NH; ++g) a += sc[g] * Vl[g][c];
            ao[c] = a * inv;
        }
        // out proj + residual
        float xa[CH];
#pragma unroll
        for (int c = 0; c < CH; ++c) {
            float o = bo[c];
#pragma unroll
            for (int j = 0; j < CH; ++j) o += ao[j] * Wo[c * CH + j];
            xa[c] = xp[c] + o;
        }
        // LayerNorm 2
        float mu = 0.f;
#pragma unroll
        for (int c = 0; c < CH; ++c) mu += xa[c];
        mu *= 0.125f;
        float var = 0.f;
#pragma unroll
        for (int c = 0; c < CH; ++c) { float d = xa[c] - mu; var += d * d; }
        var *= 0.125f;
        float rs = rsqrtf(var + EPS);
        float xn2[CH];
#pragma unroll
        for (int c = 0; c < CH; ++c) xn2[c] = (xa[c] - mu) * rs * g2[c] + beta2[c];
        // FFN (exact gelu)
        float h1[HID];
#pragma unroll
        for (int i = 0; i < HID; ++i) {
            float t = b1[i];
#pragma unroll
            for (int c = 0; c < CH; ++c) t += xn2[c] * W1[i * CH + c];
            h1[i] = 0.5f * t * (1.0f + erff(t * 0.70710678118654752f));
        }
        const float gs = 1.0f / (1.0f + __expf(-gate[0]));
#pragma unroll
        for (int c = 0; c < CH; ++c) {
            float f = b2[c];
#pragma unroll
            for (int i = 0; i < HID; ++i) f += h1[i] * W2[c * HID + i];
            float xo = xa[c] + f;
            fac[tid][c] = 1.0f + gs * (xo - xp[c]) + xp[c];
        }
    }
    __syncthreads();
    const float f = fac[hh][cc];

    const nf4* xs = (const nf4*)x + (size_t)half * HALF4;
    nf4*       os = (nf4*)out     + (size_t)half * HALF4;
    int k = tid;
#pragma unroll
    for (int it = 0; it < 8; ++it) {      // 8 iters x 4 independent load+store
        nf4 v0 = xs[k];
        nf4 v1 = xs[k + 256];
        nf4 v2 = xs[k + 512];
        nf4 v3 = xs[k + 768];
        v0 *= f; v1 *= f; v2 *= f; v3 *= f;
        __builtin_nontemporal_store(v0, &os[k]);
        __builtin_nontemporal_store(v1, &os[k + 256]);
        __builtin_nontemporal_store(v2, &os[k + 512]);
        __builtin_nontemporal_store(v3, &os[k + 768]);
        k += 1024;
    }
}

extern "C" void kernel_launch(void* const* d_in, const int* in_sizes, int n_in,
                              void* d_out, int out_size, void* d_ws, size_t ws_size,
                              hipStream_t stream) {
    const float* x     = (const float*)d_in[0];
    const float* Wq    = (const float*)d_in[1];
    const float* Wk    = (const float*)d_in[2];
    const float* Wv    = (const float*)d_in[3];
    const float* Wo    = (const float*)d_in[4];
    const float* bo    = (const float*)d_in[5];
    const float* W1    = (const float*)d_in[6];
    const float* b1    = (const float*)d_in[7];
    const float* W2    = (const float*)d_in[8];
    const float* b2    = (const float*)d_in[9];
    const float* g1    = (const float*)d_in[10];
    const float* beta1 = (const float*)d_in[11];
    const float* g2    = (const float*)d_in[12];
    const float* beta2 = (const float*)d_in[13];
    const float* gate  = (const float*)d_in[14];
    float* out = (float*)d_out;

    float* partial = (float*)d_ws;           // NHALF floats

    pool_kernel<<<NHALF, 256, 0, stream>>>(x, partial);
    scale_fused<<<NHALF, 256, 0, stream>>>(x, partial,
                                           Wq, Wk, Wv, Wo, bo,
                                           W1, b1, W2, b2,
                                           g1, beta1, g2, beta2,
                                           gate, out);
}